// Round 10
// baseline (112.453 us; speedup 1.0000x reference)
//
#include <hip/hip_runtime.h>

// Problem constants: N=50000, E=100000, F=80000, B=64, S=32, T=32, D=3
#define NB      64
#define SS      32
#define TT      32
#define RADIUSF 1.1f
#define NROWS   34                  // delta bins: s* in [0,32], s*+1 in [1,33]
#define NCNT    128                 // blocks for count/build passes
#define HSTRIDE (NROWS * 64 + 1)    // 2177 words: +1 depads banks for the merge

// ---------- k_pre: node heights + per-block EF bucket counts + {cur=0, ns} ----------
__global__ __launch_bounds__(256) void k_pre(
    const float* __restrict__ x, const float* __restrict__ v,
    const int* __restrict__ ei, const int* __restrict__ fc,
    const int* __restrict__ batch,
    float* __restrict__ nh, int* __restrict__ cntp,
    int* __restrict__ cur, int* __restrict__ ns,
    int Nn, int E, int F, int nhBlocks)
{
    const int tid = threadIdx.x;
    if ((int)blockIdx.x < nhBlocks) {
        const int idx = blockIdx.x * 256 + tid;
        if (idx >= Nn * TT) return;
        const int n = idx >> 5, t = idx & 31;
        nh[idx] = x[3 * n] * v[t] + x[3 * n + 1] * v[TT + t] + x[3 * n + 2] * v[2 * TT + t];
    } else if ((int)blockIdx.x < nhBlocks + NCNT) {
        __shared__ int lc[NB];
        const int blk = blockIdx.x - nhBlocks;      // 0..NCNT-1
        const int EF = E + F;
        if (tid < NB) lc[tid] = 0;
        __syncthreads();
        const int j0 = (int)((long long)EF * blk / NCNT);
        const int j1 = (int)((long long)EF * (blk + 1) / NCNT);
        for (int j = j0 + tid; j < j1; j += 256) {
            const int i0 = (j < E) ? ei[j] : fc[j - E];
            atomicAdd(&lc[batch[i0]], 1);           // LDS only
        }
        __syncthreads();
        if (tid < NB) cntp[blk * NB + tid] = lc[tid];
    } else {
        // tail block: zero reservation counters + node ranges via binary search
        if (tid < NB) cur[tid] = 0;
        if (tid <= NB) {
            int lo = 0, hi = Nn;
            while (lo < hi) { const int mid = (lo + hi) >> 1; if (batch[mid] < tid) lo = mid + 1; else hi = mid; }
            ns[tid] = lo;
        }
    }
}

// ---------- k_build: redundant per-block prefix + scatter EF into U ----------
__global__ __launch_bounds__(256) void k_build(
    const float* __restrict__ nw, const int* __restrict__ ei,
    const int* __restrict__ fc, const int* __restrict__ batch,
    const int* __restrict__ cntp, int* __restrict__ cur,
    int* __restrict__ ebase_g, int4* __restrict__ U, int E, int F)
{
    __shared__ int s_sum[4][NB];
    __shared__ int s_base[NB + 1];
    __shared__ int lc[NB];
    __shared__ int lb[NB];
    const int tid = threadIdx.x;
    const int EF = E + F;

    // every block computes the 64-bucket prefix itself (32 KB of L2 reads)
    {
        const int bb = tid & 63, q = tid >> 6;
        int s = 0;
        for (int blk = q * (NCNT / 4); blk < (q + 1) * (NCNT / 4); ++blk)
            s += cntp[blk * NB + bb];
        s_sum[q][bb] = s;
    }
    __syncthreads();
    if (tid == 0) {
        int run = 0;
        for (int b = 0; b < NB; ++b) {
            s_base[b] = run;
            run += s_sum[0][b] + s_sum[1][b] + s_sum[2][b] + s_sum[3][b];
        }
        s_base[NB] = run;
    }
    if (tid < NB) lc[tid] = 0;
    __syncthreads();
    if (blockIdx.x == 0 && tid <= NB) ebase_g[tid] = s_base[tid];

    const int j0 = (int)((long long)EF * blockIdx.x / NCNT);
    const int j1 = (int)((long long)EF * (blockIdx.x + 1) / NCNT);
    // pass 1: count my slice per bucket
    for (int j = j0 + tid; j < j1; j += 256) {
        const int i0 = (j < E) ? ei[j] : fc[j - E];
        atomicAdd(&lc[batch[i0]], 1);
    }
    __syncthreads();
    if (tid < NB) { const int c = lc[tid]; lb[tid] = c ? atomicAdd(&cur[tid], c) : 0; lc[tid] = 0; }
    __syncthreads();
    // pass 2: write edges/faces at reserved slots (contiguous per bucket per block)
    for (int j = j0 + tid; j < j1; j += 256) {
        int i0, i1, i2; float w;
        if (j < E) {
            i0 = ei[j]; i1 = ei[E + j]; i2 = i0;
            w = -fmaxf(nw[i0], nw[i1]);
        } else {
            const int f = j - E;
            i0 = fc[f]; i1 = fc[F + f]; i2 = fc[2 * F + f];
            w = fmaxf(nw[i0], fmaxf(nw[i1], nw[i2]));
        }
        const int b = batch[i0];
        const int r = atomicAdd(&lc[b], 1);
        U[s_base[b] + lb[b] + r] = make_int4(i0, i1, i2, __float_as_int(w));
    }
}

// ---------- k_main3: one block per graph; 16 private hists; merge+prefix -> out ----------
__global__ __launch_bounds__(1024) void k_main3(
    const float* __restrict__ nh, const float* __restrict__ nw,
    const int4* __restrict__ U, const int* __restrict__ ns,
    const int* __restrict__ ebase, float* __restrict__ out)
{
    __shared__ float hist[16 * HSTRIDE];    // 139,328 B (gfx950: up to 160 KB/WG)
    __shared__ float tile[SS * TT];

    const int tid  = threadIdx.x;
    const int wave = tid >> 6;
    const int lane = tid & 63;
    const int t    = lane & 31;
    const int half = lane >> 5;
    const int b    = blockIdx.x;

    float* H = hist + wave * HSTRIDE;
    for (int i = tid; i < 16 * HSTRIDE; i += 1024) hist[i] = 0.0f;
    __syncthreads();

    const float INV = 31.0f / 2.2f;
    const float DLT = 2.2f / 31.0f;

    // s* = rint((h+R)/step); sigma* = 1/(1+exp(500*(h - lin[s*])));
    // lin[s*] = s**step - R  =>  h - lin[s*] = (h + R) - s**step
#define BODY(hv, wv)                                                        \
    {                                                                       \
        const float hr = hv + RADIUSF;                                      \
        float sf = rintf(hr * INV);                                         \
        sf = fminf(fmaxf(sf, 0.0f), 32.0f);                                 \
        const float t1 = __builtin_fmaf(sf, -DLT, hr);                      \
        const float Ee = __expf(500.0f * t1);                               \
        const float sg = __builtin_amdgcn_rcpf(1.0f + Ee);                  \
        const float dA = wv * sg;                                           \
        const float dB = wv - dA;                                           \
        float* p = H + (int)sf * 64 + lane;                                 \
        p[0]  += dA;                                                        \
        p[64] += dB;                                                        \
    }

    // ---- nodes of graph b: contiguous in nh/nw, no staging needed ----
    const int n0 = ns[b], n1 = ns[b + 1];
    for (int k = n0 + wave * 2; k < n1; k += 32) {
        int n = k + half;
        const bool valid = (n < n1);
        if (!valid) n = k;
        const float h = nh[n * 32 + t];
        const float w = nw[n];
        if (valid) BODY(h, w)
    }

    // ---- edges+faces of graph b: contiguous slice of U ----
    const int e0 = ebase[b], e1 = ebase[b + 1];
    for (int k = e0 + wave * 2; k < e1; k += 32) {
        const int kk = k + half;
        const bool valid = (kk < e1);
        const int4 q = U[valid ? kk : k];
        const float h = fminf(nh[q.x * 32 + t],
                        fminf(nh[q.y * 32 + t], nh[q.z * 32 + t]));
        const float w = __int_as_float(q.w);
        if (valid) BODY(h, w)
    }
#undef BODY

    __syncthreads();
    // merge 16 hists x 2 halves -> tile[s][t]  (bank-safe: HSTRIDE depads wv)
    {
        const int s = tid >> 5, t2 = tid & 31;
        float acc = 0.0f;
#pragma unroll
        for (int wv = 0; wv < 16; ++wv) {
            const float* hp = hist + wv * HSTRIDE + s * 64 + t2;
            acc += hp[0] + hp[32];
        }
        tile[tid] = acc;
    }
    __syncthreads();
    // prefix over s (reads are broadcast per step) -> out[b][s][t]
    {
        const int s = tid >> 5, t2 = tid & 31;
        float run = 0.0f;
        for (int sp = 0; sp <= s; ++sp) run += tile[(sp << 5) + t2];
        out[((size_t)b << 10) + tid] = run;
    }
}

extern "C" void kernel_launch(void* const* d_in, const int* in_sizes, int n_in,
                              void* d_out, int out_size, void* d_ws, size_t ws_size,
                              hipStream_t stream)
{
    const float* x     = (const float*)d_in[0];
    const float* nw    = (const float*)d_in[1];
    const float* v     = (const float*)d_in[2];
    const int*   ei    = (const int*)d_in[4];
    const int*   fc    = (const int*)d_in[5];
    const int*   batch = (const int*)d_in[6];
    float*       out   = (float*)d_out;

    const int Nn = in_sizes[1];
    const int E  = in_sizes[4] / 2;
    const int F  = in_sizes[5] / 3;
    const int EF = E + F;

    auto align256 = [](size_t v_) { return (v_ + 255) & ~(size_t)255; };
    const size_t nh_b = align256((size_t)Nn * TT * sizeof(float));   // 6.4 MB
    const size_t U_b  = align256((size_t)EF * sizeof(int4));         // 2.9 MB

    float* nh    = (float*)d_ws;
    int4*  U     = (int4*)((char*)d_ws + nh_b);
    int*   cntp  = (int*)((char*)d_ws + nh_b + U_b);   // [NCNT*64]
    int*   cur   = cntp + NCNT * NB;                   // [64]
    int*   ns    = cur + 64;                           // [65]
    int*   ebase = ns + 72;                            // [65]

    const int nhBlocks = (Nn * TT + 255) / 256;
    k_pre  <<<nhBlocks + NCNT + 1, 256, 0, stream>>>(x, v, ei, fc, batch, nh, cntp,
                                                     cur, ns, Nn, E, F, nhBlocks);
    k_build<<<NCNT, 256, 0, stream>>>(nw, ei, fc, batch, cntp, cur, ebase, U, E, F);
    k_main3<<<NB, 1024, 0, stream>>>(nh, nw, U, ns, ebase, out);
}

// Round 11
// 51.665 us; speedup vs baseline: 2.1766x; 2.1766x over previous
//
#include <hip/hip_runtime.h>

// Problem constants: N=50000, E=100000, F=80000, B=64, S=32, T=32, D=3
#define NB      64
#define SS      32
#define TT      32
#define RADIUSF 1.1f
#define NC      16              // chunks per graph -> grid = 16*64 = 1024 = 4 blocks/CU
#define NROWS   34              // delta bins: s* in [0,32], s*+1 in [1,33]
#define NCNT    128             // blocks for count/build passes

// ---------- k_pre: node heights + per-block EF bucket counts + {cur=0, ns} ----------
__global__ __launch_bounds__(256) void k_pre(
    const float* __restrict__ x, const float* __restrict__ v,
    const int* __restrict__ ei, const int* __restrict__ fc,
    const int* __restrict__ batch,
    float* __restrict__ nh, int* __restrict__ cntp,
    int* __restrict__ cur, int* __restrict__ ns,
    int Nn, int E, int F, int nhBlocks)
{
    const int tid = threadIdx.x;
    if ((int)blockIdx.x < nhBlocks) {
        const int idx = blockIdx.x * 256 + tid;
        if (idx >= Nn * TT) return;
        const int n = idx >> 5, t = idx & 31;
        nh[idx] = x[3 * n] * v[t] + x[3 * n + 1] * v[TT + t] + x[3 * n + 2] * v[2 * TT + t];
    } else if ((int)blockIdx.x < nhBlocks + NCNT) {
        __shared__ int lc[NB];
        const int blk = blockIdx.x - nhBlocks;      // 0..NCNT-1
        const int EF = E + F;
        if (tid < NB) lc[tid] = 0;
        __syncthreads();
        const int j0 = (int)((long long)EF * blk / NCNT);
        const int j1 = (int)((long long)EF * (blk + 1) / NCNT);
        for (int j = j0 + tid; j < j1; j += 256) {
            const int i0 = (j < E) ? ei[j] : fc[j - E];
            atomicAdd(&lc[batch[i0]], 1);           // LDS only
        }
        __syncthreads();
        if (tid < NB) cntp[blk * NB + tid] = lc[tid];
    } else {
        // tail block: zero reservation counters + node ranges via binary search
        if (tid < NB) cur[tid] = 0;
        if (tid <= NB) {
            int lo = 0, hi = Nn;
            while (lo < hi) { const int mid = (lo + hi) >> 1; if (batch[mid] < tid) lo = mid + 1; else hi = mid; }
            ns[tid] = lo;
        }
    }
}

// ---------- k_build: redundant per-block prefix + scatter EF into U ----------
__global__ __launch_bounds__(256) void k_build(
    const float* __restrict__ nw, const int* __restrict__ ei,
    const int* __restrict__ fc, const int* __restrict__ batch,
    const int* __restrict__ cntp, int* __restrict__ cur,
    int* __restrict__ ebase_g, int4* __restrict__ U, int E, int F)
{
    __shared__ int s_sum[4][NB];
    __shared__ int s_base[NB + 1];
    __shared__ int lc[NB];
    __shared__ int lb[NB];
    const int tid = threadIdx.x;
    const int EF = E + F;

    // every block computes the 64-bucket prefix itself (32 KB of L2 reads)
    {
        const int bb = tid & 63, q = tid >> 6;
        int s = 0;
        for (int blk = q * (NCNT / 4); blk < (q + 1) * (NCNT / 4); ++blk)
            s += cntp[blk * NB + bb];
        s_sum[q][bb] = s;
    }
    __syncthreads();
    if (tid == 0) {
        int run = 0;
        for (int b = 0; b < NB; ++b) {
            s_base[b] = run;
            run += s_sum[0][b] + s_sum[1][b] + s_sum[2][b] + s_sum[3][b];
        }
        s_base[NB] = run;
    }
    if (tid < NB) lc[tid] = 0;
    __syncthreads();
    if (blockIdx.x == 0 && tid <= NB) ebase_g[tid] = s_base[tid];

    const int j0 = (int)((long long)EF * blockIdx.x / NCNT);
    const int j1 = (int)((long long)EF * (blockIdx.x + 1) / NCNT);
    // pass 1: count my slice per bucket
    for (int j = j0 + tid; j < j1; j += 256) {
        const int i0 = (j < E) ? ei[j] : fc[j - E];
        atomicAdd(&lc[batch[i0]], 1);
    }
    __syncthreads();
    if (tid < NB) { const int c = lc[tid]; lb[tid] = c ? atomicAdd(&cur[tid], c) : 0; lc[tid] = 0; }
    __syncthreads();
    // pass 2: write edges/faces at reserved slots
    for (int j = j0 + tid; j < j1; j += 256) {
        int i0, i1, i2; float w;
        if (j < E) {
            i0 = ei[j]; i1 = ei[E + j]; i2 = i0;
            w = -fmaxf(nw[i0], nw[i1]);
        } else {
            const int f = j - E;
            i0 = fc[f]; i1 = fc[F + f]; i2 = fc[2 * F + f];
            w = fmaxf(nw[i0], fmaxf(nw[i1], nw[i2]));
        }
        const int b = batch[i0];
        const int r = atomicAdd(&lc[b], 1);
        U[s_base[b] + lb[b] + r] = make_int4(i0, i1, i2, __float_as_int(w));
    }
}

// ---------- k_main2: (b,chunk) blocks; per-wave private hist; q-prefetch ----------
__global__ __launch_bounds__(256) void k_main2(
    const float* __restrict__ nh, const float* __restrict__ nw,
    const int4* __restrict__ U, const int* __restrict__ ns,
    const int* __restrict__ ebase, float* __restrict__ partial)
{
    __shared__ float hist[4][NROWS * 64];

    const int tid  = threadIdx.x;
    const int wave = tid >> 6;
    const int lane = tid & 63;
    const int t    = lane & 31;
    const int half = lane >> 5;
    const int b     = blockIdx.x & 63;      // XCD-aligned: all chunks of b on XCD b%8
    const int chunk = blockIdx.x >> 6;

    float* H = hist[wave];
    for (int i = tid; i < 4 * NROWS * 64; i += 256) ((float*)hist)[i] = 0.0f;
    __syncthreads();

    const float INV = 31.0f / 2.2f;
    const float DLT = 2.2f / 31.0f;

    // s* = rint((h+R)/step); sigma* = 1/(1+exp(500*(h - lin[s*])))
#define BODY(hv, wv)                                                        \
    {                                                                       \
        const float hr = hv + RADIUSF;                                      \
        float sf = rintf(hr * INV);                                         \
        sf = fminf(fmaxf(sf, 0.0f), 32.0f);                                 \
        const float t1 = __builtin_fmaf(sf, -DLT, hr);                      \
        const float Ee = __expf(500.0f * t1);                               \
        const float sg = __builtin_amdgcn_rcpf(1.0f + Ee);                  \
        const float dA = wv * sg;                                           \
        const float dB = wv - dA;                                           \
        float* p = H + (int)sf * 64 + lane;                                 \
        p[0]  += dA;                                                        \
        p[64] += dB;                                                        \
    }

    // ---- nodes of graph b: contiguous in nh/nw ----
    {
        const int g0 = ns[b], g1 = ns[b + 1];
        const int gc = g1 - g0;
        const int m0 = g0 + (int)(((long long)gc * chunk) / NC);
        const int m1 = g0 + (int)(((long long)gc * (chunk + 1)) / NC);
        for (int k = m0 + wave * 2; k < m1; k += 8) {
            const int n = min(k + half, m1 - 1);
            const float h = nh[n * 32 + t];
            const float w = nw[n];
            if (k + half < m1) BODY(h, w)
        }
    }

    // ---- edges+faces of graph b: contiguous slice of U, next-q prefetch ----
    {
        const int g0 = ebase[b], g1 = ebase[b + 1];
        const int gc = g1 - g0;
        const int m0 = g0 + (int)(((long long)gc * chunk) / NC);
        const int m1 = g0 + (int)(((long long)gc * (chunk + 1)) / NC);
        int k = m0 + wave * 2;
        if (k < m1) {
            int4 q = U[min(k + half, m1 - 1)];
            while (k < m1) {
                const int kn = k + 8;
                const int4 qn = U[min(kn + half, m1 - 1)];   // prefetch next iter
                const float h = fminf(nh[q.x * 32 + t],
                                fminf(nh[q.y * 32 + t], nh[q.z * 32 + t]));
                const float w = __int_as_float(q.w);
                if (k + half < m1) BODY(h, w)
                q = qn;
                k = kn;
            }
        }
    }
#undef BODY

    __syncthreads();
    // flush rows 0..31 -> partial[block][s*32+t2]
    float* dst = partial + ((size_t)blockIdx.x << 10);
    for (int i = tid; i < SS * TT; i += 256) {
        const int s = i >> 5, t2 = i & 31;
        float acc = 0.0f;
#pragma unroll
        for (int wv = 0; wv < 4; ++wv)
            acc += hist[wv][s * 64 + t2] + hist[wv][s * 64 + t2 + 32];
        dst[i] = acc;
    }
}

// ---------- finish: one block per graph; reduce chunks + prefix over s ----------
__global__ __launch_bounds__(1024) void k_finish(
    const float* __restrict__ partial, float* __restrict__ out)
{
    __shared__ float tile[SS * TT];
    const int b   = blockIdx.x;
    const int tid = threadIdx.x;            // cell = s*32 + t
    float acc = 0.0f;
#pragma unroll
    for (int c = 0; c < NC; ++c) acc += partial[(((size_t)(c * NB + b)) << 10) + tid];
    tile[tid] = acc;
    __syncthreads();
    const int t = tid & 31, s = tid >> 5;
    float run = 0.0f;
    for (int sp = 0; sp <= s; ++sp) run += tile[(sp << 5) + t];
    out[((size_t)b << 10) + tid] = run;
}

extern "C" void kernel_launch(void* const* d_in, const int* in_sizes, int n_in,
                              void* d_out, int out_size, void* d_ws, size_t ws_size,
                              hipStream_t stream)
{
    const float* x     = (const float*)d_in[0];
    const float* nw    = (const float*)d_in[1];
    const float* v     = (const float*)d_in[2];
    const int*   ei    = (const int*)d_in[4];
    const int*   fc    = (const int*)d_in[5];
    const int*   batch = (const int*)d_in[6];
    float*       out   = (float*)d_out;

    const int Nn = in_sizes[1];
    const int E  = in_sizes[4] / 2;
    const int F  = in_sizes[5] / 3;
    const int EF = E + F;

    auto align256 = [](size_t v_) { return (v_ + 255) & ~(size_t)255; };
    const size_t nh_b   = align256((size_t)Nn * TT * sizeof(float));              // 6.4 MB
    const size_t U_b    = align256((size_t)EF * sizeof(int4));                    // 2.9 MB
    const size_t part_b = align256((size_t)NC * NB * SS * TT * sizeof(float));    // 4 MB

    float* nh      = (float*)d_ws;
    int4*  U       = (int4*)((char*)d_ws + nh_b);
    float* partial = (float*)((char*)d_ws + nh_b + U_b);
    int*   cntp    = (int*)((char*)d_ws + nh_b + U_b + part_b);   // [NCNT*64]
    int*   cur     = cntp + NCNT * NB;                            // [64]
    int*   ns      = cur + 64;                                    // [65]
    int*   ebase   = ns + 72;                                     // [65]

    const int nhBlocks = (Nn * TT + 255) / 256;
    k_pre   <<<nhBlocks + NCNT + 1, 256, 0, stream>>>(x, v, ei, fc, batch, nh, cntp,
                                                      cur, ns, Nn, E, F, nhBlocks);
    k_build <<<NCNT, 256, 0, stream>>>(nw, ei, fc, batch, cntp, cur, ebase, U, E, F);
    k_main2 <<<NC * NB, 256, 0, stream>>>(nh, nw, U, ns, ebase, partial);
    k_finish<<<NB, 1024, 0, stream>>>(partial, out);
}

// Round 12
// 38.777 us; speedup vs baseline: 2.9000x; 1.3324x over previous
//
#include <hip/hip_runtime.h>

// Problem constants: N=50000, E=100000, F=80000, B=64, S=32, T=32, D=3
#define NB      64
#define SS      32
#define TT      32
#define RADIUSF 1.1f
#define NC      16              // chunks per graph -> grid = 16*64 = 1024 = 4 blocks/CU
#define NROWS   34              // delta bins: s* in [0,32], s*+1 in [1,33]
#define NCNT    128             // blocks for count/build passes
#define BCAP    1440            // max EF items per build slice (180000/128 = 1407)

// ---------- k_pre-lite: per-block EF bucket counts + {cur=0, ns ranges} ----------
__global__ __launch_bounds__(256) void k_pre(
    const int* __restrict__ ei, const int* __restrict__ fc,
    const int* __restrict__ batch,
    int* __restrict__ cntp, int* __restrict__ cur, int* __restrict__ ns,
    int Nn, int E, int F)
{
    const int tid = threadIdx.x;
    if ((int)blockIdx.x < NCNT) {
        __shared__ int lc[NB];
        const int blk = blockIdx.x;
        const int EF = E + F;
        if (tid < NB) lc[tid] = 0;
        __syncthreads();
        const int j0 = (int)((long long)EF * blk / NCNT);
        const int j1 = (int)((long long)EF * (blk + 1) / NCNT);
        for (int j = j0 + tid; j < j1; j += 256) {
            const int i0 = (j < E) ? ei[j] : fc[j - E];
            atomicAdd(&lc[batch[i0]], 1);           // LDS only
        }
        __syncthreads();
        if (tid < NB) cntp[blk * NB + tid] = lc[tid];
    } else {
        // tail block: zero reservation counters + node ranges via binary search
        if (tid < NB) cur[tid] = 0;
        if (tid <= NB) {
            int lo = 0, hi = Nn;
            while (lo < hi) { const int mid = (lo + hi) >> 1; if (batch[mid] < tid) lo = mid + 1; else hi = mid; }
            ns[tid] = lo;
        }
    }
}

// ---------- k_build: per-block prefix + LDS record cache + scatter EF into U ----------
__global__ __launch_bounds__(256) void k_build(
    const float* __restrict__ nw, const int* __restrict__ ei,
    const int* __restrict__ fc, const int* __restrict__ batch,
    const int* __restrict__ cntp, int* __restrict__ cur,
    int* __restrict__ ebase_g, int4* __restrict__ U, int E, int F)
{
    __shared__ int s_sum[4][NB];
    __shared__ int s_base[NB + 1];
    __shared__ int lc[NB];
    __shared__ int lb[NB];
    __shared__ int   r_i0[BCAP], r_i1[BCAP], r_i2[BCAP];
    __shared__ float r_w[BCAP];
    __shared__ unsigned char r_b[BCAP];
    const int tid = threadIdx.x;
    const int EF = E + F;

    // every block computes the 64-bucket prefix itself (32 KB of L2 reads)
    {
        const int bb = tid & 63, q = tid >> 6;
        int s = 0;
        for (int blk = q * (NCNT / 4); blk < (q + 1) * (NCNT / 4); ++blk)
            s += cntp[blk * NB + bb];
        s_sum[q][bb] = s;
    }
    __syncthreads();
    if (tid == 0) {
        int run = 0;
        for (int b = 0; b < NB; ++b) {
            s_base[b] = run;
            run += s_sum[0][b] + s_sum[1][b] + s_sum[2][b] + s_sum[3][b];
        }
        s_base[NB] = run;
    }
    if (tid < NB) lc[tid] = 0;
    __syncthreads();
    if (blockIdx.x == 0 && tid <= NB) ebase_g[tid] = s_base[tid];

    const int j0 = (int)((long long)EF * blockIdx.x / NCNT);
    const int j1 = (int)((long long)EF * (blockIdx.x + 1) / NCNT);
    // pass 1: load/gather once, stash record in LDS, count per bucket
    for (int j = j0 + tid, idx = tid; j < j1; j += 256, idx += 256) {
        int i0, i1, i2; float w;
        if (j < E) {
            i0 = ei[j]; i1 = ei[E + j]; i2 = i0;
            w = -fmaxf(nw[i0], nw[i1]);
        } else {
            const int f = j - E;
            i0 = fc[f]; i1 = fc[F + f]; i2 = fc[2 * F + f];
            w = fmaxf(nw[i0], fmaxf(nw[i1], nw[i2]));
        }
        const int b = batch[i0];
        r_i0[idx] = i0; r_i1[idx] = i1; r_i2[idx] = i2;
        r_w[idx] = w; r_b[idx] = (unsigned char)b;
        atomicAdd(&lc[b], 1);
    }
    __syncthreads();
    if (tid < NB) { const int c = lc[tid]; lb[tid] = c ? atomicAdd(&cur[tid], c) : 0; lc[tid] = 0; }
    __syncthreads();
    // pass 2: write from LDS records at reserved slots (no global re-gathers)
    const int cnt = j1 - j0;
    for (int idx = tid; idx < cnt; idx += 256) {
        const int b = r_b[idx];
        const int r = atomicAdd(&lc[b], 1);
        U[s_base[b] + lb[b] + r] =
            make_int4(r_i0[idx], r_i1[idx], r_i2[idx], __float_as_int(r_w[idx]));
    }
}

// ---------- k_main2: (b,chunk) blocks; x-direct heights; per-wave private hist ----------
__global__ __launch_bounds__(256) void k_main2(
    const float* __restrict__ x, const float* __restrict__ nw,
    const float* __restrict__ v, const int4* __restrict__ U,
    const int* __restrict__ ns, const int* __restrict__ ebase,
    float* __restrict__ partial)
{
    __shared__ float hist[4][NROWS * 64];

    const int tid  = threadIdx.x;
    const int wave = tid >> 6;
    const int lane = tid & 63;
    const int t    = lane & 31;
    const int half = lane >> 5;
    const int b     = blockIdx.x & 63;      // XCD-aligned: all chunks of b on XCD b%8
    const int chunk = blockIdx.x >> 6;

    float* H = hist[wave];
    for (int i = tid; i < 4 * NROWS * 64; i += 256) ((float*)hist)[i] = 0.0f;
    __syncthreads();

    // v column for this lane's theta (3 regs)
    const float v0 = v[t], v1 = v[TT + t], v2 = v[2 * TT + t];

    const float INV = 31.0f / 2.2f;
    const float DLT = 2.2f / 31.0f;

    // s* = rint((h+R)/step); sigma* = 1/(1+exp(500*(h - lin[s*])))
#define BODY(hv, wv)                                                        \
    {                                                                       \
        const float hr = hv + RADIUSF;                                      \
        float sf = rintf(hr * INV);                                         \
        sf = fminf(fmaxf(sf, 0.0f), 32.0f);                                 \
        const float t1 = __builtin_fmaf(sf, -DLT, hr);                      \
        const float Ee = __expf(500.0f * t1);                               \
        const float sg = __builtin_amdgcn_rcpf(1.0f + Ee);                  \
        const float dA = wv * sg;                                           \
        const float dB = wv - dA;                                           \
        float* p = H + (int)sf * 64 + lane;                                 \
        p[0]  += dA;                                                        \
        p[64] += dB;                                                        \
    }

    // ---- nodes of graph b: contiguous range; h computed from x directly ----
    {
        const int g0 = ns[b], g1 = ns[b + 1];
        const int gc = g1 - g0;
        const int m0 = g0 + (int)(((long long)gc * chunk) / NC);
        const int m1 = g0 + (int)(((long long)gc * (chunk + 1)) / NC);
        for (int k = m0 + wave * 2; k < m1; k += 8) {
            const int n = min(k + half, m1 - 1);
            const float x0 = x[3 * n], x1 = x[3 * n + 1], x2 = x[3 * n + 2];
            const float h = __builtin_fmaf(x0, v0, __builtin_fmaf(x1, v1, x2 * v2));
            const float w = nw[n];
            if (k + half < m1) BODY(h, w)
        }
    }

    // ---- edges+faces of graph b: contiguous slice of U; next-q prefetch ----
    {
        const int g0 = ebase[b], g1 = ebase[b + 1];
        const int gc = g1 - g0;
        const int m0 = g0 + (int)(((long long)gc * chunk) / NC);
        const int m1 = g0 + (int)(((long long)gc * (chunk + 1)) / NC);
        int k = m0 + wave * 2;
        if (k < m1) {
            int4 q = U[min(k + half, m1 - 1)];
            while (k < m1) {
                const int kn = k + 8;
                const int4 qn = U[min(kn + half, m1 - 1)];   // prefetch next iter
                const float a0 = x[3 * q.x], a1 = x[3 * q.x + 1], a2 = x[3 * q.x + 2];
                const float b0 = x[3 * q.y], b1 = x[3 * q.y + 1], b2 = x[3 * q.y + 2];
                const float c0 = x[3 * q.z], c1 = x[3 * q.z + 1], c2 = x[3 * q.z + 2];
                const float h0 = __builtin_fmaf(a0, v0, __builtin_fmaf(a1, v1, a2 * v2));
                const float h1 = __builtin_fmaf(b0, v0, __builtin_fmaf(b1, v1, b2 * v2));
                const float h2 = __builtin_fmaf(c0, v0, __builtin_fmaf(c1, v1, c2 * v2));
                const float h = fminf(h0, fminf(h1, h2));
                const float w = __int_as_float(q.w);
                if (k + half < m1) BODY(h, w)
                q = qn;
                k = kn;
            }
        }
    }
#undef BODY

    __syncthreads();
    // flush rows 0..31 -> partial[block][s*32+t2]
    float* dst = partial + ((size_t)blockIdx.x << 10);
    for (int i = tid; i < SS * TT; i += 256) {
        const int s = i >> 5, t2 = i & 31;
        float acc = 0.0f;
#pragma unroll
        for (int wv = 0; wv < 4; ++wv)
            acc += hist[wv][s * 64 + t2] + hist[wv][s * 64 + t2 + 32];
        dst[i] = acc;
    }
}

// ---------- finish: one block per graph; reduce chunks + prefix over s ----------
__global__ __launch_bounds__(1024) void k_finish(
    const float* __restrict__ partial, float* __restrict__ out)
{
    __shared__ float tile[SS * TT];
    const int b   = blockIdx.x;
    const int tid = threadIdx.x;            // cell = s*32 + t
    float acc = 0.0f;
#pragma unroll
    for (int c = 0; c < NC; ++c) acc += partial[(((size_t)(c * NB + b)) << 10) + tid];
    tile[tid] = acc;
    __syncthreads();
    const int t = tid & 31, s = tid >> 5;
    float run = 0.0f;
    for (int sp = 0; sp <= s; ++sp) run += tile[(sp << 5) + t];
    out[((size_t)b << 10) + tid] = run;
}

extern "C" void kernel_launch(void* const* d_in, const int* in_sizes, int n_in,
                              void* d_out, int out_size, void* d_ws, size_t ws_size,
                              hipStream_t stream)
{
    const float* x     = (const float*)d_in[0];
    const float* nw    = (const float*)d_in[1];
    const float* v     = (const float*)d_in[2];
    const int*   ei    = (const int*)d_in[4];
    const int*   fc    = (const int*)d_in[5];
    const int*   batch = (const int*)d_in[6];
    float*       out   = (float*)d_out;

    const int Nn = in_sizes[1];
    const int E  = in_sizes[4] / 2;
    const int F  = in_sizes[5] / 3;
    const int EF = E + F;

    auto align256 = [](size_t v_) { return (v_ + 255) & ~(size_t)255; };
    const size_t U_b    = align256((size_t)EF * sizeof(int4));                    // 2.9 MB
    const size_t part_b = align256((size_t)NC * NB * SS * TT * sizeof(float));    // 4 MB

    int4*  U       = (int4*)d_ws;
    float* partial = (float*)((char*)d_ws + U_b);
    int*   cntp    = (int*)((char*)d_ws + U_b + part_b);          // [NCNT*64]
    int*   cur     = cntp + NCNT * NB;                            // [64]
    int*   ns      = cur + 64;                                    // [65]
    int*   ebase   = ns + 72;                                     // [65]

    k_pre   <<<NCNT + 1, 256, 0, stream>>>(ei, fc, batch, cntp, cur, ns, Nn, E, F);
    k_build <<<NCNT, 256, 0, stream>>>(nw, ei, fc, batch, cntp, cur, ebase, U, E, F);
    k_main2 <<<NC * NB, 256, 0, stream>>>(x, nw, v, U, ns, ebase, partial);
    k_finish<<<NB, 1024, 0, stream>>>(partial, out);
}